// Round 1
// baseline (48.358 us; speedup 1.0000x reference)
//
#include <hip/hip_runtime.h>
#include <hip/hip_bf16.h>

#define TOKENS 16384
#define NEXP 8
#define INF 512
#define OUTF 512

#define BM 128
#define BN 128
#define BK 64

using f32x4 = __attribute__((ext_vector_type(4))) float;
using bfrag = __attribute__((ext_vector_type(8))) __bf16;

// fp32 -> bf16 RNE (inputs are finite; no NaN care needed)
__device__ __forceinline__ short f2bf(float f) {
  union { float f; unsigned u; } v; v.f = f;
  unsigned r = v.u + 0x7fffu + ((v.u >> 16) & 1u);
  return (short)(r >> 16);
}

__global__ void k_zero(int* __restrict__ cursor) {
  if (threadIdx.x < NEXP) cursor[threadIdx.x] = 0;
}

// Bucket tokens by expert into fixed per-expert regions perm[e*TOKENS ...].
// Block-aggregated atomics: 256 LDS atomics + <=8 global atomics per block.
__global__ void k_scatter(const int* __restrict__ gate, int* __restrict__ cursor,
                          int* __restrict__ perm) {
  __shared__ int lc[NEXP], lb[NEXP];
  int tid = threadIdx.x;
  if (tid < NEXP) lc[tid] = 0;
  __syncthreads();
  int t = blockIdx.x * 256 + tid;
  int e = gate[t];
  int ls = atomicAdd(&lc[e], 1);
  __syncthreads();
  if (tid < NEXP) lb[tid] = lc[tid] ? atomicAdd(&cursor[tid], lc[tid]) : 0;
  __syncthreads();
  perm[e * TOKENS + lb[e] + ls] = t;
}

// Grouped GEMM: C[tok][o] = sum_k W[e][o][k] * X[tok][k] for tokens of expert e.
// 128x128 tile, BK=64, 4 waves each computing a 64x64 quadrant via 4x4
// mfma_f32_16x16x32_bf16 fragments. Reg-staged fp32->bf16 into XOR-swizzled LDS.
__global__ __launch_bounds__(256, 2)
void moe_gemm(const float* __restrict__ inp, const float* __restrict__ weight,
              const int* __restrict__ cursor, const int* __restrict__ perm,
              float* __restrict__ out) {
  const int nt = blockIdx.x;   // 0..3   (OUTF/BN)
  const int mt = blockIdx.y;   // 0..127 (TOKENS/BM worst case)
  const int e  = blockIdx.z;   // 0..7
  const int cnt = cursor[e];
  if (mt * BM >= cnt) return;
  const int m_valid = min(BM, cnt - mt * BM);
  const int* pbase = perm + e * TOKENS + mt * BM;

  __shared__ __align__(16) short As[BM * BK];
  __shared__ __align__(16) short Bs[BN * BK];
  __shared__ int toks[BM];

  const int tid = threadIdx.x;
  if (tid < BM) {
    int r = (tid < m_valid) ? tid : 0;   // clamp invalid rows to a valid token
    toks[tid] = pbase[r];
  }
  __syncthreads();

  const int lane = tid & 63;
  const int wid  = tid >> 6;
  const int wr = wid >> 1, wc = wid & 1;   // 2x2 wave grid of 64x64 quadrants
  const int lr = lane & 15;                // fragment row/col
  const int lg = lane >> 4;                // k-group 0..3

  f32x4 acc[4][4];
#pragma unroll
  for (int i = 0; i < 4; i++)
#pragma unroll
    for (int j = 0; j < 4; j++) acc[i][j] = (f32x4)0.0f;

  const float* wbase = weight + (size_t)e * OUTF * INF + (size_t)(nt * BN) * INF;

  // Per-thread staging geometry (constant across K): 1024 chunks of 8 elems,
  // chunk = tid + 256*i -> row = chunk>>3, k8 = chunk&7. Consecutive lanes
  // cover 256B contiguous per row (coalesced).
  const float* aptr[4];
  const float* bptr[4];
  int soff[4];
#pragma unroll
  for (int i = 0; i < 4; i++) {
    int chunk = tid + 256 * i;
    int row = chunk >> 3, k8 = chunk & 7;
    aptr[i] = inp + (size_t)toks[row] * INF + k8 * 8;
    bptr[i] = wbase + (size_t)row * INF + k8 * 8;
    soff[i] = ((row * BK + k8 * 8) * 2) ^ ((row & 7) << 4);  // swizzled byte off
  }

  for (int kk = 0; kk < INF; kk += BK) {
    // ---- stage A (gathered rows, fp32->bf16) and B (weight, fp32->bf16) ----
#pragma unroll
    for (int i = 0; i < 4; i++) {
      float4 a0 = *(const float4*)(aptr[i] + kk);
      float4 a1 = *(const float4*)(aptr[i] + kk + 4);
      float4 b0 = *(const float4*)(bptr[i] + kk);
      float4 b1 = *(const float4*)(bptr[i] + kk + 4);
      using s8 = __attribute__((ext_vector_type(8))) short;
      s8 pa, pb;
      pa[0] = f2bf(a0.x); pa[1] = f2bf(a0.y); pa[2] = f2bf(a0.z); pa[3] = f2bf(a0.w);
      pa[4] = f2bf(a1.x); pa[5] = f2bf(a1.y); pa[6] = f2bf(a1.z); pa[7] = f2bf(a1.w);
      pb[0] = f2bf(b0.x); pb[1] = f2bf(b0.y); pb[2] = f2bf(b0.z); pb[3] = f2bf(b0.w);
      pb[4] = f2bf(b1.x); pb[5] = f2bf(b1.y); pb[6] = f2bf(b1.z); pb[7] = f2bf(b1.w);
      *(s8*)((char*)As + soff[i]) = pa;
      *(s8*)((char*)Bs + soff[i]) = pb;
    }
    __syncthreads();

    // ---- compute: 2 k-substeps x 4x4 fragments = 32 MFMAs per wave ----
#pragma unroll
    for (int ks = 0; ks < 2; ks++) {
      bfrag af[4], bfv[4];
#pragma unroll
      for (int i = 0; i < 4; i++) {
        int row = wr * 64 + i * 16 + lr;
        int off = ((row * BK + ks * 32 + lg * 8) * 2) ^ ((row & 7) << 4);
        af[i] = *(const bfrag*)((const char*)As + off);
      }
#pragma unroll
      for (int j = 0; j < 4; j++) {
        int row = wc * 64 + j * 16 + lr;
        int off = ((row * BK + ks * 32 + lg * 8) * 2) ^ ((row & 7) << 4);
        bfv[j] = *(const bfrag*)((const char*)Bs + off);
      }
#pragma unroll
      for (int i = 0; i < 4; i++)
#pragma unroll
        for (int j = 0; j < 4; j++)
          acc[i][j] = __builtin_amdgcn_mfma_f32_16x16x32_bf16(af[i], bfv[j],
                                                              acc[i][j], 0, 0, 0);
    }
    __syncthreads();
  }

  // ---- epilogue: C/D layout col=lane&15, row=(lane>>4)*4+reg (m89-verified) ----
#pragma unroll
  for (int i = 0; i < 4; i++) {
    int rbase = wr * 64 + i * 16 + lg * 4;
#pragma unroll
    for (int r = 0; r < 4; r++) {
      int rr = rbase + r;
      if (rr < m_valid) {
        float* orow = out + (size_t)toks[rr] * OUTF + nt * BN + wc * 64 + lr;
#pragma unroll
        for (int j = 0; j < 4; j++) orow[j * 16] = acc[i][j][r];
      }
    }
  }
}

extern "C" void kernel_launch(void* const* d_in, const int* in_sizes, int n_in,
                              void* d_out, int out_size, void* d_ws, size_t ws_size,
                              hipStream_t stream) {
  (void)in_sizes; (void)n_in; (void)out_size; (void)ws_size;
  const float* inp    = (const float*)d_in[0];
  const int*   gate   = (const int*)d_in[1];
  const float* weight = (const float*)d_in[2];
  float* out = (float*)d_out;

  int* cursor = (int*)d_ws;       // 8 ints
  int* perm   = cursor + 16;      // NEXP * TOKENS ints

  k_zero<<<1, 64, 0, stream>>>(cursor);
  k_scatter<<<TOKENS / 256, 256, 0, stream>>>(gate, cursor, perm);
  dim3 grid(OUTF / BN, TOKENS / BM, NEXP);
  moe_gemm<<<grid, 256, 0, stream>>>(inp, weight, cursor, perm, out);
}

// Round 2
// 47.526 us; speedup vs baseline: 1.0175x; 1.0175x over previous
//
#include <hip/hip_runtime.h>
#include <hip/hip_bf16.h>

#define TOKENS 16384
#define NEXP 8
#define INF 512
#define OUTF 512

#define BM 128
#define BN 128
#define BK 64

using f32x4 = __attribute__((ext_vector_type(4))) float;
using bfrag = __attribute__((ext_vector_type(8))) __bf16;
using s8v   = __attribute__((ext_vector_type(8))) short;

// fp32 -> bf16 RNE
__device__ __forceinline__ short f2bf(float f) {
  union { float f; unsigned u; } v; v.f = f;
  unsigned r = v.u + 0x7fffu + ((v.u >> 16) & 1u);
  return (short)(r >> 16);
}

__device__ __forceinline__ void gload16(const void* g, void* l) {
  __builtin_amdgcn_global_load_lds(
      (const __attribute__((address_space(1))) unsigned int*)g,
      (__attribute__((address_space(3))) unsigned int*)l, 16, 0, 0);
}

__device__ __forceinline__ bfrag cvt8(f32x4 lo, f32x4 hi) {
  bfrag r;
  r[0] = (__bf16)lo[0]; r[1] = (__bf16)lo[1];
  r[2] = (__bf16)lo[2]; r[3] = (__bf16)lo[3];
  r[4] = (__bf16)hi[0]; r[5] = (__bf16)hi[1];
  r[6] = (__bf16)hi[2]; r[7] = (__bf16)hi[3];
  return r;
}

__global__ void k_zero(int* __restrict__ cursor) {
  if (threadIdx.x < NEXP) cursor[threadIdx.x] = 0;
}

// weight fp32 -> bf16, contiguous [E][O][I]; 8 elems/thread
__global__ void k_convw(const float* __restrict__ w, s8v* __restrict__ wb) {
  int idx = blockIdx.x * 256 + threadIdx.x;
  const float4* src = (const float4*)w + (size_t)idx * 2;
  float4 a = src[0], b = src[1];
  s8v p;
  p[0] = f2bf(a.x); p[1] = f2bf(a.y); p[2] = f2bf(a.z); p[3] = f2bf(a.w);
  p[4] = f2bf(b.x); p[5] = f2bf(b.y); p[6] = f2bf(b.z); p[7] = f2bf(b.w);
  wb[idx] = p;
}

// Bucket tokens by expert (block-aggregated atomics).
__global__ void k_scatter(const int* __restrict__ gate, int* __restrict__ cursor,
                          int* __restrict__ perm) {
  __shared__ int lc[NEXP], lb[NEXP];
  int tid = threadIdx.x;
  if (tid < NEXP) lc[tid] = 0;
  __syncthreads();
  int t = blockIdx.x * 256 + tid;
  int e = gate[t];
  int ls = atomicAdd(&lc[e], 1);
  __syncthreads();
  if (tid < NEXP) lb[tid] = lc[tid] ? atomicAdd(&cursor[tid], lc[tid]) : 0;
  __syncthreads();
  perm[e * TOKENS + lb[e] + ls] = t;
}

// Grouped GEMM. A: fp32 gathered rows via global_load_lds (cvt to bf16 in regs).
// B: pre-converted bf16 weight via global_load_lds. Both tiles bank-swizzled by
// permuting the per-lane GLOBAL source chunk (LDS dest linear) + identical XOR
// on the ds_read side (rule #21: both-sides-or-neither).
__global__ __launch_bounds__(256, 2)
void moe_gemm(const float* __restrict__ inp, const short* __restrict__ wb,
              const int* __restrict__ cursor, const int* __restrict__ perm,
              float* __restrict__ out) {
  const int nt = blockIdx.x;   // 0..3
  const int mt = blockIdx.y;   // 0..127
  const int e  = blockIdx.z;   // 0..7
  const int cnt = cursor[e];
  if (mt * BM >= cnt) return;
  const int m_valid = min(BM, cnt - mt * BM);
  const int* pbase = perm + e * TOKENS + mt * BM;

  __shared__ __align__(16) float As[BM * BK];   // 32 KB, swizzled by 16B chunk
  __shared__ __align__(16) short Bs[BN * BK];   // 16 KB, swizzled by 16B chunk
  __shared__ int toks[BM];

  const int tid = threadIdx.x;
  if (tid < BM) toks[tid] = pbase[(tid < m_valid) ? tid : 0];
  __syncthreads();

  const int lane = tid & 63;
  const int wid  = tid >> 6;
  const int wr = wid >> 1, wc = wid & 1;
  const int lr = lane & 15;
  const int lg = lane >> 4;

  // ---- staging geometry (constant across K) ----
  // A: 2048 phys chunks of 16B; site s covers chunks s*256+tid.
  //    row = s*16 + (tid>>4); c_phys = tid&15; c_log = c_phys ^ (row&15).
  const int arl  = tid >> 4;                 // row&15 for all sites
  const int aclog = (tid & 15) ^ arl;
  const float* agp[8];
#pragma unroll
  for (int s = 0; s < 8; s++)
    agp[s] = inp + (size_t)toks[s * 16 + arl] * INF + aclog * 4;
  char* alds = (char*)As + wid * 1024;       // wave-uniform base

  // B: 1024 phys chunks; site s covers chunks s*256+tid.
  //    row = s*32 + (tid>>3); c_phys = tid&7; c_log = c_phys ^ (row&7).
  const int brl  = tid >> 3;                 // 0..31
  const int bclog = (tid & 7) ^ (brl & 7);
  const short* bgp[4];
  const short* wbase = wb + (size_t)e * OUTF * INF + (size_t)(nt * BN) * INF;
#pragma unroll
  for (int s = 0; s < 4; s++)
    bgp[s] = wbase + (size_t)(s * 32 + brl) * INF + bclog * 8;
  char* blds = (char*)Bs + wid * 1024;

  f32x4 acc[4][4];
#pragma unroll
  for (int i = 0; i < 4; i++)
#pragma unroll
    for (int j = 0; j < 4; j++) acc[i][j] = (f32x4)0.0f;

  for (int kk = 0; kk < INF; kk += BK) {
    // ---- stage tile kk (direct-to-LDS, 16B) ----
#pragma unroll
    for (int s = 0; s < 8; s++) gload16(agp[s] + kk, alds + s * 4096);
#pragma unroll
    for (int s = 0; s < 4; s++) gload16(bgp[s] + kk, blds + s * 4096);
    __syncthreads();

    // ---- compute: 2 ks x 4x4 frags = 32 MFMA / wave ----
#pragma unroll
    for (int ks = 0; ks < 2; ks++) {
      bfrag af[4], bfv[4];
#pragma unroll
      for (int i = 0; i < 4; i++) {
        int row = wr * 64 + i * 16 + lr;
        int c = ks * 8 + lg * 2;
        f32x4 lo = *(const f32x4*)((const char*)As + row * 256 + ((c     ^ (row & 15)) * 16));
        f32x4 hi = *(const f32x4*)((const char*)As + row * 256 + (((c+1) ^ (row & 15)) * 16));
        af[i] = cvt8(lo, hi);
      }
#pragma unroll
      for (int j = 0; j < 4; j++) {
        int row = wc * 64 + j * 16 + lr;
        int c = ks * 4 + lg;
        bfv[j] = *(const bfrag*)((const char*)Bs + row * 128 + ((c ^ (row & 7)) * 16));
      }
#pragma unroll
      for (int i = 0; i < 4; i++)
#pragma unroll
        for (int j = 0; j < 4; j++)
          acc[i][j] = __builtin_amdgcn_mfma_f32_16x16x32_bf16(af[i], bfv[j],
                                                              acc[i][j], 0, 0, 0);
    }
    __syncthreads();
  }

  // ---- epilogue: C/D col=lane&15, row=(lane>>4)*4+reg ----
#pragma unroll
  for (int i = 0; i < 4; i++) {
    int rbase = wr * 64 + i * 16 + lg * 4;
#pragma unroll
    for (int r = 0; r < 4; r++) {
      int rr = rbase + r;
      if (rr < m_valid) {
        float* orow = out + (size_t)toks[rr] * OUTF + nt * BN + wc * 64 + lr;
#pragma unroll
        for (int j = 0; j < 4; j++) orow[j * 16] = acc[i][j][r];
      }
    }
  }
}

extern "C" void kernel_launch(void* const* d_in, const int* in_sizes, int n_in,
                              void* d_out, int out_size, void* d_ws, size_t ws_size,
                              hipStream_t stream) {
  (void)in_sizes; (void)n_in; (void)out_size; (void)ws_size;
  const float* inp    = (const float*)d_in[0];
  const int*   gate   = (const int*)d_in[1];
  const float* weight = (const float*)d_in[2];
  float* out = (float*)d_out;

  int*   cursor = (int*)d_ws;                          // 8 ints
  int*   perm   = (int*)((char*)d_ws + 1024);          // 512 KB
  short* wbf    = (short*)((char*)d_ws + (1 << 20));   // 4 MB bf16 weight

  k_zero<<<1, 64, 0, stream>>>(cursor);
  k_convw<<<(NEXP * OUTF * INF) / (256 * 8), 256, 0, stream>>>(weight, (s8v*)wbf);
  k_scatter<<<TOKENS / 256, 256, 0, stream>>>(gate, cursor, perm);
  dim3 grid(OUTF / BN, TOKENS / BM, NEXP);
  moe_gemm<<<grid, 256, 0, stream>>>(inp, wbf, cursor, perm, out);
}